// Round 1
// baseline (309.844 us; speedup 1.0000x reference)
//
#include <hip/hip_runtime.h>
#include <hip/hip_bf16.h>

typedef __attribute__((ext_vector_type(8))) short short8;
typedef __attribute__((ext_vector_type(4))) float f32x4;

#define B_   4
#define S_   2048
#define D_   1024
#define H_   16
#define HD_  64
#define M_   (B_ * S_)      // 8192
#define N3_  (3 * D_)       // 3072

#define GLDS16(g, l)                                                        \
  __builtin_amdgcn_global_load_lds(                                         \
      (const __attribute__((address_space(1))) void*)(g),                   \
      (__attribute__((address_space(3))) void*)(l), 16, 0, 0)

__device__ __forceinline__ unsigned pack_bf2(float a, float b) {
  union { __hip_bfloat16 h; unsigned short s; } ua, ub;
  ua.h = __float2bfloat16(a);
  ub.h = __float2bfloat16(b);
  return (unsigned)ua.s | ((unsigned)ub.s << 16);
}

// ---------------------------------------------------------------- casts ----
__global__ __launch_bounds__(256) void cast_f32_bf16(
    const float* __restrict__ in, __hip_bfloat16* __restrict__ out, int n) {
  int i = (blockIdx.x * 256 + threadIdx.x) * 4;
  if (i + 3 < n) {
    float4 v = *(const float4*)(in + i);
    union { ushort4 u4; __hip_bfloat16 h[4]; } p;
    p.h[0] = __float2bfloat16(v.x);
    p.h[1] = __float2bfloat16(v.y);
    p.h[2] = __float2bfloat16(v.z);
    p.h[3] = __float2bfloat16(v.w);
    *(ushort4*)(out + i) = p.u4;
  }
}

// in: [rows][cols] fp32 -> out: [cols][rows] bf16
__global__ __launch_bounds__(256) void transpose_cast(
    const float* __restrict__ in, __hip_bfloat16* __restrict__ out,
    int rows, int cols) {
  __shared__ float tile[32][33];
  int bx = blockIdx.x * 32;
  int by = blockIdx.y * 32;
  int tx = threadIdx.x, ty = threadIdx.y;   // (32, 8)
#pragma unroll
  for (int i = 0; i < 4; ++i)
    tile[ty + i * 8][tx] = in[(size_t)(by + ty + i * 8) * cols + bx + tx];
  __syncthreads();
#pragma unroll
  for (int i = 0; i < 4; ++i)
    out[(size_t)(bx + ty + i * 8) * rows + by + tx] =
        __float2bfloat16(tile[tx][ty + i * 8]);
}

// ----------------------------------------------------------------- GEMM ----
__device__ inline void store_out(float* p, float v) { *p = v; }
__device__ inline void store_out(__hip_bfloat16* p, float v) {
  *p = __float2bfloat16(v);
}

template <typename OUT_T, bool WVT>
__global__ __launch_bounds__(256) void gemm_bt_bias(
    const __hip_bfloat16* __restrict__ A, const __hip_bfloat16* __restrict__ Bt,
    const float* __restrict__ bias, OUT_T* __restrict__ C,
    __hip_bfloat16* __restrict__ vt, int M, int N, int K) {
  __shared__ __align__(16) __hip_bfloat16 Alds[128 * 64];
  __shared__ __align__(16) __hip_bfloat16 Blds[128 * 64];
  const int t = threadIdx.x;
  const int wave = t >> 6, lane = t & 63;
  const int quad = lane >> 4, l15 = lane & 15;
  const int wm = (wave >> 1) * 64, wn = (wave & 1) * 64;
  const int m0 = blockIdx.y * 128, n0 = blockIdx.x * 128;

  const int rsub = lane >> 3;
  const int gc16 = (lane & 7) ^ (rsub & 7);
  const __hip_bfloat16* gA[4];
  const __hip_bfloat16* gB[4];
  __hip_bfloat16* lA[4];
  __hip_bfloat16* lB[4];
#pragma unroll
  for (int i = 0; i < 4; ++i) {
    int c = wave * 4 + i;
    int row = c * 8 + rsub;
    gA[i] = A + (size_t)(m0 + row) * K + gc16 * 8;
    gB[i] = Bt + (size_t)(n0 + row) * K + gc16 * 8;
    lA[i] = Alds + c * 512;
    lB[i] = Blds + c * 512;
  }

  f32x4 acc[4][4] = {};

  for (int k0 = 0; k0 < K; k0 += 64) {
#pragma unroll
    for (int i = 0; i < 4; ++i) {
      GLDS16(gA[i] + k0, lA[i]);
      GLDS16(gB[i] + k0, lB[i]);
    }
    __syncthreads();
#pragma unroll
    for (int kk = 0; kk < 2; ++kk) {
      const int fo = ((kk * 4 + quad) ^ (l15 & 7)) * 8;  // swizzled frag col
      short8 a[4], bfr[4];
#pragma unroll
      for (int mt = 0; mt < 4; ++mt)
        a[mt] = *(const short8*)(Alds + (wm + mt * 16 + l15) * 64 + fo);
#pragma unroll
      for (int nt = 0; nt < 4; ++nt)
        bfr[nt] = *(const short8*)(Blds + (wn + nt * 16 + l15) * 64 + fo);
#pragma unroll
      for (int mt = 0; mt < 4; ++mt)
#pragma unroll
        for (int nt = 0; nt < 4; ++nt)
          acc[mt][nt] = __builtin_amdgcn_mfma_f32_16x16x32_bf16(
              a[mt], bfr[nt], acc[mt][nt], 0, 0, 0);
    }
    __syncthreads();
  }

  if (WVT && n0 >= 2048) {
#pragma unroll
    for (int mt = 0; mt < 4; ++mt)
#pragma unroll
      for (int nt = 0; nt < 4; ++nt) {
        int col = n0 + wn + nt * 16 + l15;
        float bv = bias[col];
        int hv = (col - 2048) >> 6, d = (col - 2048) & 63;
        int row0 = m0 + wm + mt * 16 + quad * 4;
        int bidx = row0 >> 11, s = row0 & 2047;
        uint2 w;
        w.x = pack_bf2(acc[mt][nt][0] + bv, acc[mt][nt][1] + bv);
        w.y = pack_bf2(acc[mt][nt][2] + bv, acc[mt][nt][3] + bv);
        *(uint2*)(vt + ((size_t)(bidx * 16 + hv) * 64 + d) * 2048 + s) = w;
      }
  } else {
#pragma unroll
    for (int mt = 0; mt < 4; ++mt)
#pragma unroll
      for (int nt = 0; nt < 4; ++nt) {
        int col = n0 + wn + nt * 16 + l15;
        float bv = bias[col];
#pragma unroll
        for (int r = 0; r < 4; ++r) {
          int row = m0 + wm + mt * 16 + quad * 4 + r;
          store_out(C + (size_t)row * N + col, acc[mt][nt][r] + bv);
        }
      }
  }
}

// ------------------------------------------------------ flash attention ----
// S^T formulation.  R6: latency-bound fixes.
//  * 2048 blocks (one qb each, longest-first dispatch) -> more waves in flight
//  * GLDS16 staging of K and V (pre-swizzled global source, linear LDS) --
//    removes per-iter load/ds_write glue + size_t address math (VALU diet)
//  * K/V frags prefetched to regs, then next tile's GLDS issued mid-iter so
//    the load latency hides under 36 MFMA + softmax (2-phase pipeline)
//  * XOR-swizzled LDS everywhere -> conflict-free (was 7.57M conflict cyc)
//  * LDS 27.6->24 KB: 6 blocks/CU; __launch_bounds__(128,3) caps VGPR <=170
//  * defer-max (THR=8): skip alpha-rescale unless max grew
__global__ __launch_bounds__(128, 3) void attn_causal(
    const __hip_bfloat16* __restrict__ qkv,
    const __hip_bfloat16* __restrict__ vt,
    __hip_bfloat16* __restrict__ ctx) {
  __shared__ __align__(16) __hip_bfloat16 Klds[64 * 64];       // [kpos][d]
  __shared__ __align__(16) __hip_bfloat16 Vlds[64 * 64];       // [d][kpos]
  __shared__ __align__(16) __hip_bfloat16 Plds[2][2][16][64];  // [wv][g][q][k]

  const int t = threadIdx.x;
  const int wave = t >> 6, lane = t & 63;
  const int quad = lane >> 4, l15 = lane & 15;
  const int qb = 31 - (int)blockIdx.x;   // longest blocks dispatch first (LPT)
  const int h = blockIdx.y, b = blockIdx.z;

  const size_t qbase = (size_t)b * S_ * N3_ + h * HD_;
  const size_t kbase = qbase + D_;
  const size_t vtbase = (size_t)(b * H_ + h) * HD_ * S_;
  const float C2 = 0.18033688f;  // (1/sqrt(64)) * log2(e)

  short8 ones;
#pragma unroll
  for (int j = 0; j < 8; ++j) ones[j] = (short)0x3F80;  // bf16 1.0

  // ---- Q fragments: wave owns 32 q-rows (2 groups of 16) ----
  short8 qf[2][2];
#pragma unroll
  for (int g = 0; g < 2; ++g) {
    const int qrow = qb * 64 + wave * 32 + g * 16 + l15;
    qf[g][0] = *(const short8*)(qkv + qbase + (size_t)qrow * N3_ + quad * 8);
    qf[g][1] =
        *(const short8*)(qkv + qbase + (size_t)qrow * N3_ + 32 + quad * 8);
  }

  // ---- staging: pre-swizzled global source, linear LDS dest (GEMM trick) --
  const int rsub = lane >> 3;               // row within 8-row subtile
  const int swz = ((lane & 7) ^ rsub) * 8;  // swizzled col (elements)
  const __hip_bfloat16* gK[4];
  const __hip_bfloat16* gV[4];
  __hip_bfloat16* lK[4];
  __hip_bfloat16* lV[4];
#pragma unroll
  for (int i = 0; i < 4; ++i) {
    const int c = wave * 4 + i;             // subtile id (wave-uniform base)
    gK[i] = qkv + kbase + (size_t)(c * 8 + rsub) * N3_ + swz;
    gV[i] = vt + vtbase + (size_t)(c * 8 + rsub) * S_ + swz;
    lK[i] = Klds + c * 512;
    lV[i] = Vlds + c * 512;
  }

  f32x4 o[2][4] = {};                       // O^T accum per group
  float m_r[2] = {-1e30f, -1e30f}, l_r[2] = {0.f, 0.f};

  const int fo0 = (quad ^ (l15 & 7)) * 8;        // swizzled frag col, k 0..31
  const int fo1 = ((4 + quad) ^ (l15 & 7)) * 8;  // k 32..63

  // prologue: stage tile kb=0
#pragma unroll
  for (int i = 0; i < 4; ++i) {
    GLDS16(gK[i], lK[i]);
    GLDS16(gV[i], lV[i]);
  }
  __syncthreads();

  for (int kb = 0; kb <= qb; ++kb) {
    // ---- K and V fragments -> regs (conflict-free swizzled b128 reads) ----
    short8 kf[4][2], vf[4][2];
#pragma unroll
    for (int nt = 0; nt < 4; ++nt) {
      const __hip_bfloat16* kr = Klds + (nt * 16 + l15) * 64;
      const __hip_bfloat16* vr = Vlds + (nt * 16 + l15) * 64;
      kf[nt][0] = *(const short8*)(kr + fo0);
      kf[nt][1] = *(const short8*)(kr + fo1);
      vf[nt][0] = *(const short8*)(vr + fo0);
      vf[nt][1] = *(const short8*)(vr + fo1);
    }
    __syncthreads();          // both waves done reading the tiles
    if (kb < qb) {            // prefetch next tile under compute
#pragma unroll
      for (int i = 0; i < 4; ++i) {
        gK[i] += 64 * N3_;
        gV[i] += 64;
        GLDS16(gK[i], lK[i]);
        GLDS16(gV[i], lV[i]);
      }
    }

    const bool diag = (kb == qb);
    short8 pB[2][2];
#pragma unroll
    for (int g = 0; g < 2; ++g) {
      f32x4 st[4];
#pragma unroll
      for (int nt = 0; nt < 4; ++nt) {
        f32x4 z = {};
        z = __builtin_amdgcn_mfma_f32_16x16x32_bf16(kf[nt][0], qf[g][0], z,
                                                    0, 0, 0);
        z = __builtin_amdgcn_mfma_f32_16x16x32_bf16(kf[nt][1], qf[g][1], z,
                                                    0, 0, 0);
        st[nt] = z;
      }
      if (diag) {  // mask kpos_local > qrow_local
        const int rloc = wave * 32 + g * 16 + l15;
#pragma unroll
        for (int nt = 0; nt < 4; ++nt)
#pragma unroll
          for (int r = 0; r < 4; ++r)
            if (nt * 16 + quad * 4 + r > rloc) st[nt][r] = -1e30f;
      }

      // row max over kpos: in-lane fold + cross-quad shfl
      float tm = st[0][0];
#pragma unroll
      for (int nt = 0; nt < 4; ++nt)
#pragma unroll
        for (int r = 0; r < 4; ++r) tm = fmaxf(tm, st[nt][r]);
      tm = fmaxf(tm, __shfl_xor(tm, 16));
      tm = fmaxf(tm, __shfl_xor(tm, 32));
      const float pm = tm * C2;

      // defer-max: rescale only when the running max actually grew (P <= 2^8)
      if (!__all(pm - m_r[g] <= 8.0f)) {
        const float mn = fmaxf(m_r[g], pm);
        const float al = __builtin_amdgcn_exp2f(m_r[g] - mn);
        m_r[g] = mn;
        l_r[g] *= al;
#pragma unroll
        for (int dt = 0; dt < 4; ++dt)
#pragma unroll
          for (int r = 0; r < 4; ++r) o[g][dt][r] *= al;
      }
      const float mneg = -m_r[g];

      // P = exp2(fma(st,C2,-m)); pack bf16x4 -> swizzled b64 LDS write
      __hip_bfloat16* prow = &Plds[wave][g][l15][0];
#pragma unroll
      for (int nt = 0; nt < 4; ++nt) {
        float p0 = __builtin_amdgcn_exp2f(__builtin_fmaf(st[nt][0], C2, mneg));
        float p1 = __builtin_amdgcn_exp2f(__builtin_fmaf(st[nt][1], C2, mneg));
        float p2 = __builtin_amdgcn_exp2f(__builtin_fmaf(st[nt][2], C2, mneg));
        float p3 = __builtin_amdgcn_exp2f(__builtin_fmaf(st[nt][3], C2, mneg));
        uint2 w;
        w.x = pack_bf2(p0, p1);
        w.y = pack_bf2(p2, p3);
        const int u = nt * 2 + (quad >> 1);  // logical 8-elem unit
        *(uint2*)(prow + ((u ^ (l15 & 7)) * 8 + (quad & 1) * 4)) = w;
      }
      // same-wave round trip (lgkm-ordered, no barrier)
      pB[g][0] = *(const short8*)(prow + fo0);
      pB[g][1] = *(const short8*)(prow + fo1);

      // l += rowsum(P) via ones-MFMA
      f32x4 ps = {};
      ps = __builtin_amdgcn_mfma_f32_16x16x32_bf16(ones, pB[g][0], ps, 0, 0, 0);
      ps = __builtin_amdgcn_mfma_f32_16x16x32_bf16(ones, pB[g][1], ps, 0, 0, 0);
      l_r[g] += ps[0];
    }

    // ---- PV from register-held V frags (Vlds may be restaging already) ----
#pragma unroll
    for (int dt = 0; dt < 4; ++dt)
#pragma unroll
      for (int g = 0; g < 2; ++g) {
        o[g][dt] = __builtin_amdgcn_mfma_f32_16x16x32_bf16(vf[dt][0], pB[g][0],
                                                           o[g][dt], 0, 0, 0);
        o[g][dt] = __builtin_amdgcn_mfma_f32_16x16x32_bf16(vf[dt][1], pB[g][1],
                                                           o[g][dt], 0, 0, 0);
      }
    __syncthreads();  // drains vmcnt -> next tile resident in LDS
  }

  // ---- epilogue: ctx[qrow][d] = O^T/l, packed b64 stores ----
#pragma unroll
  for (int g = 0; g < 2; ++g) {
    const float rl = __builtin_amdgcn_rcpf(l_r[g]);
    const int qrow = qb * 64 + wave * 32 + g * 16 + l15;
    __hip_bfloat16* crow = ctx + ((size_t)b * S_ + qrow) * D_ + h * HD_;
#pragma unroll
    for (int dt = 0; dt < 4; ++dt) {
      uint2 w;
      w.x = pack_bf2(o[g][dt][0] * rl, o[g][dt][1] * rl);
      w.y = pack_bf2(o[g][dt][2] * rl, o[g][dt][3] * rl);
      *(uint2*)(crow + dt * 16 + quad * 4) = w;
    }
  }
}

// --------------------------------------------------------------- launch ----
extern "C" void kernel_launch(void* const* d_in, const int* in_sizes, int n_in,
                              void* d_out, int out_size, void* d_ws,
                              size_t ws_size, hipStream_t stream) {
  const float* x      = (const float*)d_in[0];
  const float* w_qkv  = (const float*)d_in[1];
  const float* b_qkv  = (const float*)d_in[2];
  const float* w_proj = (const float*)d_in[3];
  const float* b_proj = (const float*)d_in[4];
  float* out = (float*)d_out;

  char* ws = (char*)d_ws;
  __hip_bfloat16* xb     = (__hip_bfloat16*)(ws + 0);          // 16 MB
  __hip_bfloat16* wqkvT  = (__hip_bfloat16*)(ws + 16777216);   // 6 MB
  __hip_bfloat16* wprojT = (__hip_bfloat16*)(ws + 23068672);   // 2 MB
  __hip_bfloat16* qkvb   = (__hip_bfloat16*)(ws + 25165824);   // 50.3 MB
  __hip_bfloat16* ctx    = (__hip_bfloat16*)(ws + 75497472);   // 16 MB
  __hip_bfloat16* vt2    = (__hip_bfloat16*)(ws + 91750400);   // 16 MB

  cast_f32_bf16<<<8192, 256, 0, stream>>>(x, xb, M_ * D_);
  transpose_cast<<<dim3(N3_ / 32, D_ / 32), dim3(32, 8), 0, stream>>>(
      w_qkv, wqkvT, D_, N3_);
  transpose_cast<<<dim3(D_ / 32, D_ / 32), dim3(32, 8), 0, stream>>>(
      w_proj, wprojT, D_, D_);

  gemm_bt_bias<__hip_bfloat16, true>
      <<<dim3(N3_ / 128, M_ / 128), 256, 0, stream>>>(
          xb, wqkvT, b_qkv, qkvb, vt2, M_, N3_, D_);

  attn_causal<<<dim3(32, H_, B_), 128, 0, stream>>>(qkvb, vt2, ctx);

  gemm_bt_bias<float, false><<<dim3(D_ / 128, M_ / 128), 256, 0, stream>>>(
      ctx, wprojT, b_proj, out, (__hip_bfloat16*)nullptr, M_, D_, D_);
}

// Round 2
// 295.410 us; speedup vs baseline: 1.0489x; 1.0489x over previous
//
#include <hip/hip_runtime.h>
#include <hip/hip_bf16.h>

typedef __attribute__((ext_vector_type(8))) short short8;
typedef __attribute__((ext_vector_type(4))) float f32x4;

#define B_   4
#define S_   2048
#define D_   1024
#define H_   16
#define HD_  64
#define M_   (B_ * S_)      // 8192
#define N3_  (3 * D_)       // 3072

#define GLDS16(g, l)                                                        \
  __builtin_amdgcn_global_load_lds(                                         \
      (const __attribute__((address_space(1))) void*)(g),                   \
      (__attribute__((address_space(3))) void*)(l), 16, 0, 0)

__device__ __forceinline__ unsigned pack_bf2(float a, float b) {
  union { __hip_bfloat16 h; unsigned short s; } ua, ub;
  ua.h = __float2bfloat16(a);
  ub.h = __float2bfloat16(b);
  return (unsigned)ua.s | ((unsigned)ub.s << 16);
}

// ---------------------------------------------------------------- casts ----
__global__ __launch_bounds__(256) void cast_f32_bf16(
    const float* __restrict__ in, __hip_bfloat16* __restrict__ out, int n) {
  int i = (blockIdx.x * 256 + threadIdx.x) * 4;
  if (i + 3 < n) {
    float4 v = *(const float4*)(in + i);
    union { ushort4 u4; __hip_bfloat16 h[4]; } p;
    p.h[0] = __float2bfloat16(v.x);
    p.h[1] = __float2bfloat16(v.y);
    p.h[2] = __float2bfloat16(v.z);
    p.h[3] = __float2bfloat16(v.w);
    *(ushort4*)(out + i) = p.u4;
  }
}

// in: [rows][cols] fp32 -> out: [cols][rows] bf16
__global__ __launch_bounds__(256) void transpose_cast(
    const float* __restrict__ in, __hip_bfloat16* __restrict__ out,
    int rows, int cols) {
  __shared__ float tile[32][33];
  int bx = blockIdx.x * 32;
  int by = blockIdx.y * 32;
  int tx = threadIdx.x, ty = threadIdx.y;   // (32, 8)
#pragma unroll
  for (int i = 0; i < 4; ++i)
    tile[ty + i * 8][tx] = in[(size_t)(by + ty + i * 8) * cols + bx + tx];
  __syncthreads();
#pragma unroll
  for (int i = 0; i < 4; ++i)
    out[(size_t)(bx + ty + i * 8) * rows + by + tx] =
        __float2bfloat16(tile[tx][ty + i * 8]);
}

// ----------------------------------------------------------------- GEMM ----
__device__ inline void store_out(float* p, float v) { *p = v; }
__device__ inline void store_out(__hip_bfloat16* p, float v) {
  *p = __float2bfloat16(v);
}

template <typename OUT_T, bool WVT>
__global__ __launch_bounds__(256) void gemm_bt_bias(
    const __hip_bfloat16* __restrict__ A, const __hip_bfloat16* __restrict__ Bt,
    const float* __restrict__ bias, OUT_T* __restrict__ C,
    __hip_bfloat16* __restrict__ vt, int M, int N, int K) {
  __shared__ __align__(16) __hip_bfloat16 Alds[128 * 64];
  __shared__ __align__(16) __hip_bfloat16 Blds[128 * 64];
  const int t = threadIdx.x;
  const int wave = t >> 6, lane = t & 63;
  const int quad = lane >> 4, l15 = lane & 15;
  const int wm = (wave >> 1) * 64, wn = (wave & 1) * 64;
  const int m0 = blockIdx.y * 128, n0 = blockIdx.x * 128;

  const int rsub = lane >> 3;
  const int gc16 = (lane & 7) ^ (rsub & 7);
  const __hip_bfloat16* gA[4];
  const __hip_bfloat16* gB[4];
  __hip_bfloat16* lA[4];
  __hip_bfloat16* lB[4];
#pragma unroll
  for (int i = 0; i < 4; ++i) {
    int c = wave * 4 + i;
    int row = c * 8 + rsub;
    gA[i] = A + (size_t)(m0 + row) * K + gc16 * 8;
    gB[i] = Bt + (size_t)(n0 + row) * K + gc16 * 8;
    lA[i] = Alds + c * 512;
    lB[i] = Blds + c * 512;
  }

  f32x4 acc[4][4] = {};

  for (int k0 = 0; k0 < K; k0 += 64) {
#pragma unroll
    for (int i = 0; i < 4; ++i) {
      GLDS16(gA[i] + k0, lA[i]);
      GLDS16(gB[i] + k0, lB[i]);
    }
    __syncthreads();
#pragma unroll
    for (int kk = 0; kk < 2; ++kk) {
      const int fo = ((kk * 4 + quad) ^ (l15 & 7)) * 8;  // swizzled frag col
      short8 a[4], bfr[4];
#pragma unroll
      for (int mt = 0; mt < 4; ++mt)
        a[mt] = *(const short8*)(Alds + (wm + mt * 16 + l15) * 64 + fo);
#pragma unroll
      for (int nt = 0; nt < 4; ++nt)
        bfr[nt] = *(const short8*)(Blds + (wn + nt * 16 + l15) * 64 + fo);
#pragma unroll
      for (int mt = 0; mt < 4; ++mt)
#pragma unroll
        for (int nt = 0; nt < 4; ++nt)
          acc[mt][nt] = __builtin_amdgcn_mfma_f32_16x16x32_bf16(
              a[mt], bfr[nt], acc[mt][nt], 0, 0, 0);
    }
    __syncthreads();
  }

  if (WVT && n0 >= 2048) {
#pragma unroll
    for (int mt = 0; mt < 4; ++mt)
#pragma unroll
      for (int nt = 0; nt < 4; ++nt) {
        int col = n0 + wn + nt * 16 + l15;
        float bv = bias[col];
        int hv = (col - 2048) >> 6, d = (col - 2048) & 63;
        int row0 = m0 + wm + mt * 16 + quad * 4;
        int bidx = row0 >> 11, s = row0 & 2047;
        uint2 w;
        w.x = pack_bf2(acc[mt][nt][0] + bv, acc[mt][nt][1] + bv);
        w.y = pack_bf2(acc[mt][nt][2] + bv, acc[mt][nt][3] + bv);
        *(uint2*)(vt + ((size_t)(bidx * 16 + hv) * 64 + d) * 2048 + s) = w;
      }
  } else {
#pragma unroll
    for (int mt = 0; mt < 4; ++mt)
#pragma unroll
      for (int nt = 0; nt < 4; ++nt) {
        int col = n0 + wn + nt * 16 + l15;
        float bv = bias[col];
#pragma unroll
        for (int r = 0; r < 4; ++r) {
          int row = m0 + wm + mt * 16 + quad * 4 + r;
          store_out(C + (size_t)row * N + col, acc[mt][nt][r] + bv);
        }
      }
  }
}

// ------------------------------------------------------ flash attention ----
// R7: R5's balanced sel-pairing (1024 blocks, exactly 33 iters each — the
// load-balance R6 destroyed) + R6's pipe wins + deeper pipeline:
//  * double-buffered K/V LDS -> ONE barrier per iteration (was 2); prefetch
//    of tile kb+1 issued at iteration top, landed by the barrier's vmcnt drain
//  * GLDS16 staging, pre-swizzled global source, linear LDS dest
//  * V-frags read just before PV (buf[cur] intact all iteration under dbuf)
//  * seamless sel transition: last iter of sel0 prefetches tile 0 for sel1
//    (K/V tiles depend only on kb); both sels' Q-frags hoisted to entry
//  * conflict-free XOR-swizzled frag reads; defer-max (THR=8)
//  * LDS 40KB -> 4 blocks/CU = grid cap (1024/256); launch_bounds(128,2)
__global__ __launch_bounds__(128, 2) void attn_causal(
    const __hip_bfloat16* __restrict__ qkv,
    const __hip_bfloat16* __restrict__ vt,
    __hip_bfloat16* __restrict__ ctx) {
  __shared__ __align__(16) __hip_bfloat16 Klds[2][64 * 64];    // [buf][kpos][d]
  __shared__ __align__(16) __hip_bfloat16 Vlds[2][64 * 64];    // [buf][d][kpos]
  __shared__ __align__(16) __hip_bfloat16 Plds[2][2][16][64];  // [wv][g][q][k]

  const int t = threadIdx.x;
  const int wave = t >> 6, lane = t & 63;
  const int quad = lane >> 4, l15 = lane & 15;
  const int xb = blockIdx.x, h = blockIdx.y, b = blockIdx.z;

  const size_t qbase = (size_t)b * S_ * N3_ + h * HD_;
  const size_t kbase = qbase + D_;
  const size_t vtbase = (size_t)(b * H_ + h) * HD_ * S_;
  const float C2 = 0.18033688f;  // (1/sqrt(64)) * log2(e)

  short8 ones;
#pragma unroll
  for (int j = 0; j < 8; ++j) ones[j] = (short)0x3F80;  // bf16 1.0

  // ---- Q fragments for BOTH sels, hoisted to entry ----
  short8 qf[2][2][2];  // [sel][g][frag]
#pragma unroll
  for (int sel = 0; sel < 2; ++sel) {
    const int qb = sel ? 31 - xb : xb;
#pragma unroll
    for (int g = 0; g < 2; ++g) {
      const int qrow = qb * 64 + wave * 32 + g * 16 + l15;
      qf[sel][g][0] =
          *(const short8*)(qkv + qbase + (size_t)qrow * N3_ + quad * 8);
      qf[sel][g][1] =
          *(const short8*)(qkv + qbase + (size_t)qrow * N3_ + 32 + quad * 8);
    }
  }

  // ---- staging: pre-swizzled global source, linear LDS dest ----
  const int rsub = lane >> 3;               // row within 8-row subtile
  const int swz = ((lane & 7) ^ rsub) * 8;  // swizzled col (elements)
  const __hip_bfloat16* gK[4];              // tile-0 bases
  const __hip_bfloat16* gV[4];
  __hip_bfloat16* lK[4];                    // buf-0 dests
  __hip_bfloat16* lV[4];
#pragma unroll
  for (int i = 0; i < 4; ++i) {
    const int c = wave * 4 + i;             // subtile id (wave-uniform base)
    gK[i] = qkv + kbase + (size_t)(c * 8 + rsub) * N3_ + swz;
    gV[i] = vt + vtbase + (size_t)(c * 8 + rsub) * S_ + swz;
    lK[i] = &Klds[0][c * 512];
    lV[i] = &Vlds[0][c * 512];
  }

  const int fo0 = (quad ^ (l15 & 7)) * 8;        // swizzled frag col, k 0..31
  const int fo1 = ((4 + quad) ^ (l15 & 7)) * 8;  // k 32..63

  // prologue: stage tile 0 -> buf 0
#pragma unroll
  for (int i = 0; i < 4; ++i) {
    GLDS16(gK[i], lK[i]);
    GLDS16(gV[i], lV[i]);
  }
  __syncthreads();
  int cur = 0;

  for (int sel = 0; sel < 2; ++sel) {
    const int qb = sel ? 31 - xb : xb;

    f32x4 o[2][4] = {};                     // O^T accum per group
    float m_r[2] = {-1e30f, -1e30f}, l_r[2] = {0.f, 0.f};

    for (int kb = 0; kb <= qb; ++kb) {
      // ---- prefetch next tile into buf[cur^1] (tile 0 at sel boundary) ----
      if (sel == 0 || kb < qb) {
        const size_t nk = (kb < qb) ? (size_t)(kb + 1) : 0;
        const size_t ko = nk * (size_t)(64 * N3_);
        const size_t vo = nk * 64;
        const int nb = (cur ^ 1) * 4096;
#pragma unroll
        for (int i = 0; i < 4; ++i) {
          GLDS16(gK[i] + ko, lK[i] + nb);
          GLDS16(gV[i] + vo, lV[i] + nb);
        }
      }

      const __hip_bfloat16* Kb = &Klds[cur][0];
      const __hip_bfloat16* Vb = &Vlds[cur][0];

      // ---- K fragments -> regs (conflict-free swizzled b128 reads) ----
      short8 kf[4][2];
#pragma unroll
      for (int nt = 0; nt < 4; ++nt) {
        const __hip_bfloat16* kr = Kb + (nt * 16 + l15) * 64;
        kf[nt][0] = *(const short8*)(kr + fo0);
        kf[nt][1] = *(const short8*)(kr + fo1);
      }

      const bool diag = (kb == qb);
      short8 pB[2][2];
#pragma unroll
      for (int g = 0; g < 2; ++g) {
        f32x4 st[4];
#pragma unroll
        for (int nt = 0; nt < 4; ++nt) {
          f32x4 z = {};
          z = __builtin_amdgcn_mfma_f32_16x16x32_bf16(kf[nt][0], qf[sel][g][0],
                                                      z, 0, 0, 0);
          z = __builtin_amdgcn_mfma_f32_16x16x32_bf16(kf[nt][1], qf[sel][g][1],
                                                      z, 0, 0, 0);
          st[nt] = z;
        }
        if (diag) {  // mask kpos_local > qrow_local
          const int rloc = wave * 32 + g * 16 + l15;
#pragma unroll
          for (int nt = 0; nt < 4; ++nt)
#pragma unroll
            for (int r = 0; r < 4; ++r)
              if (nt * 16 + quad * 4 + r > rloc) st[nt][r] = -1e30f;
        }

        // row max over kpos: in-lane fold + cross-quad shfl
        float tm = st[0][0];
#pragma unroll
        for (int nt = 0; nt < 4; ++nt)
#pragma unroll
          for (int r = 0; r < 4; ++r) tm = fmaxf(tm, st[nt][r]);
        tm = fmaxf(tm, __shfl_xor(tm, 16));
        tm = fmaxf(tm, __shfl_xor(tm, 32));
        const float pm = tm * C2;

        // defer-max: rescale only when the running max grew (P <= 2^8)
        if (!__all(pm - m_r[g] <= 8.0f)) {
          const float mn = fmaxf(m_r[g], pm);
          const float al = __builtin_amdgcn_exp2f(m_r[g] - mn);
          m_r[g] = mn;
          l_r[g] *= al;
#pragma unroll
          for (int dt = 0; dt < 4; ++dt)
#pragma unroll
            for (int r = 0; r < 4; ++r) o[g][dt][r] *= al;
        }
        const float mneg = -m_r[g];

        // P = exp2(fma(st,C2,-m)); pack bf16x4 -> swizzled b64 LDS write
        __hip_bfloat16* prow = &Plds[wave][g][l15][0];
#pragma unroll
        for (int nt = 0; nt < 4; ++nt) {
          float p0 =
              __builtin_amdgcn_exp2f(__builtin_fmaf(st[nt][0], C2, mneg));
          float p1 =
              __builtin_amdgcn_exp2f(__builtin_fmaf(st[nt][1], C2, mneg));
          float p2 =
              __builtin_amdgcn_exp2f(__builtin_fmaf(st[nt][2], C2, mneg));
          float p3 =
              __builtin_amdgcn_exp2f(__builtin_fmaf(st[nt][3], C2, mneg));
          uint2 w;
          w.x = pack_bf2(p0, p1);
          w.y = pack_bf2(p2, p3);
          const int u = nt * 2 + (quad >> 1);  // logical 8-elem unit
          *(uint2*)(prow + ((u ^ (l15 & 7)) * 8 + (quad & 1) * 4)) = w;
        }
        // same-wave round trip (lgkm-ordered, no barrier)
        pB[g][0] = *(const short8*)(prow + fo0);
        pB[g][1] = *(const short8*)(prow + fo1);

        // l += rowsum(P) via ones-MFMA
        f32x4 ps = {};
        ps = __builtin_amdgcn_mfma_f32_16x16x32_bf16(ones, pB[g][0], ps,
                                                     0, 0, 0);
        ps = __builtin_amdgcn_mfma_f32_16x16x32_bf16(ones, pB[g][1], ps,
                                                     0, 0, 0);
        l_r[g] += ps[0];
      }

      // ---- V fragments just before PV (buf[cur] intact under dbuf) ----
      short8 vf[4][2];
#pragma unroll
      for (int dt = 0; dt < 4; ++dt) {
        const __hip_bfloat16* vr = Vb + (dt * 16 + l15) * 64;
        vf[dt][0] = *(const short8*)(vr + fo0);
        vf[dt][1] = *(const short8*)(vr + fo1);
      }
#pragma unroll
      for (int dt = 0; dt < 4; ++dt)
#pragma unroll
        for (int g = 0; g < 2; ++g) {
          o[g][dt] = __builtin_amdgcn_mfma_f32_16x16x32_bf16(
              vf[dt][0], pB[g][0], o[g][dt], 0, 0, 0);
          o[g][dt] = __builtin_amdgcn_mfma_f32_16x16x32_bf16(
              vf[dt][1], pB[g][1], o[g][dt], 0, 0, 0);
        }

      __syncthreads();  // lands prefetch (vmcnt) + guards buf reuse
      cur ^= 1;
    }

    // ---- epilogue: ctx[qrow][d] = O^T/l (no LDS -> no barrier needed) ----
#pragma unroll
    for (int g = 0; g < 2; ++g) {
      const float rl = __builtin_amdgcn_rcpf(l_r[g]);
      const int qrow = qb * 64 + wave * 32 + g * 16 + l15;
      __hip_bfloat16* crow = ctx + ((size_t)b * S_ + qrow) * D_ + h * HD_;
#pragma unroll
      for (int dt = 0; dt < 4; ++dt) {
        uint2 w;
        w.x = pack_bf2(o[g][dt][0] * rl, o[g][dt][1] * rl);
        w.y = pack_bf2(o[g][dt][2] * rl, o[g][dt][3] * rl);
        *(uint2*)(crow + dt * 16 + quad * 4) = w;
      }
    }
  }
}

// --------------------------------------------------------------- launch ----
extern "C" void kernel_launch(void* const* d_in, const int* in_sizes, int n_in,
                              void* d_out, int out_size, void* d_ws,
                              size_t ws_size, hipStream_t stream) {
  const float* x      = (const float*)d_in[0];
  const float* w_qkv  = (const float*)d_in[1];
  const float* b_qkv  = (const float*)d_in[2];
  const float* w_proj = (const float*)d_in[3];
  const float* b_proj = (const float*)d_in[4];
  float* out = (float*)d_out;

  char* ws = (char*)d_ws;
  __hip_bfloat16* xb     = (__hip_bfloat16*)(ws + 0);          // 16 MB
  __hip_bfloat16* wqkvT  = (__hip_bfloat16*)(ws + 16777216);   // 6 MB
  __hip_bfloat16* wprojT = (__hip_bfloat16*)(ws + 23068672);   // 2 MB
  __hip_bfloat16* qkvb   = (__hip_bfloat16*)(ws + 25165824);   // 50.3 MB
  __hip_bfloat16* ctx    = (__hip_bfloat16*)(ws + 75497472);   // 16 MB
  __hip_bfloat16* vt2    = (__hip_bfloat16*)(ws + 91750400);   // 16 MB

  cast_f32_bf16<<<8192, 256, 0, stream>>>(x, xb, M_ * D_);
  transpose_cast<<<dim3(N3_ / 32, D_ / 32), dim3(32, 8), 0, stream>>>(
      w_qkv, wqkvT, D_, N3_);
  transpose_cast<<<dim3(D_ / 32, D_ / 32), dim3(32, 8), 0, stream>>>(
      w_proj, wprojT, D_, D_);

  gemm_bt_bias<__hip_bfloat16, true>
      <<<dim3(N3_ / 128, M_ / 128), 256, 0, stream>>>(
          xb, wqkvT, b_qkv, qkvb, vt2, M_, N3_, D_);

  attn_causal<<<dim3(16, H_, B_), 128, 0, stream>>>(qkvb, vt2, ctx);

  gemm_bt_bias<float, false><<<dim3(D_ / 128, M_ / 128), 256, 0, stream>>>(
      ctx, wprojT, b_proj, out, (__hip_bfloat16*)nullptr, M_, D_, D_);
}

// Round 3
// 280.767 us; speedup vs baseline: 1.1036x; 1.0522x over previous
//
#include <hip/hip_runtime.h>
#include <hip/hip_bf16.h>

typedef __attribute__((ext_vector_type(8))) short short8;
typedef __attribute__((ext_vector_type(4))) float f32x4;

#define B_   4
#define S_   2048
#define D_   1024
#define H_   16
#define HD_  64
#define M_   (B_ * S_)      // 8192
#define N3_  (3 * D_)       // 3072

#define GLDS16(g, l)                                                        \
  __builtin_amdgcn_global_load_lds(                                         \
      (const __attribute__((address_space(1))) void*)(g),                   \
      (__attribute__((address_space(3))) void*)(l), 16, 0, 0)

__device__ __forceinline__ unsigned pack_bf2(float a, float b) {
  union { __hip_bfloat16 h; unsigned short s; } ua, ub;
  ua.h = __float2bfloat16(a);
  ub.h = __float2bfloat16(b);
  return (unsigned)ua.s | ((unsigned)ub.s << 16);
}

// ---------------------------------------------------------------- casts ----
__global__ __launch_bounds__(256) void cast_f32_bf16(
    const float* __restrict__ in, __hip_bfloat16* __restrict__ out, int n) {
  int i = (blockIdx.x * 256 + threadIdx.x) * 4;
  if (i + 3 < n) {
    float4 v = *(const float4*)(in + i);
    union { ushort4 u4; __hip_bfloat16 h[4]; } p;
    p.h[0] = __float2bfloat16(v.x);
    p.h[1] = __float2bfloat16(v.y);
    p.h[2] = __float2bfloat16(v.z);
    p.h[3] = __float2bfloat16(v.w);
    *(ushort4*)(out + i) = p.u4;
  }
}

// in: [rows][cols] fp32 -> out: [cols][rows] bf16
__global__ __launch_bounds__(256) void transpose_cast(
    const float* __restrict__ in, __hip_bfloat16* __restrict__ out,
    int rows, int cols) {
  __shared__ float tile[32][33];
  int bx = blockIdx.x * 32;
  int by = blockIdx.y * 32;
  int tx = threadIdx.x, ty = threadIdx.y;   // (32, 8)
#pragma unroll
  for (int i = 0; i < 4; ++i)
    tile[ty + i * 8][tx] = in[(size_t)(by + ty + i * 8) * cols + bx + tx];
  __syncthreads();
#pragma unroll
  for (int i = 0; i < 4; ++i)
    out[(size_t)(bx + ty + i * 8) * rows + by + tx] =
        __float2bfloat16(tile[tx][ty + i * 8]);
}

// ----------------------------------------------------------------- GEMM ----
__device__ inline void store_out(float* p, float v) { *p = v; }
__device__ inline void store_out(__hip_bfloat16* p, float v) {
  *p = __float2bfloat16(v);
}

template <typename OUT_T, bool WVT>
__global__ __launch_bounds__(256) void gemm_bt_bias(
    const __hip_bfloat16* __restrict__ A, const __hip_bfloat16* __restrict__ Bt,
    const float* __restrict__ bias, OUT_T* __restrict__ C,
    __hip_bfloat16* __restrict__ vt, int M, int N, int K) {
  __shared__ __align__(16) __hip_bfloat16 Alds[128 * 64];
  __shared__ __align__(16) __hip_bfloat16 Blds[128 * 64];
  const int t = threadIdx.x;
  const int wave = t >> 6, lane = t & 63;
  const int quad = lane >> 4, l15 = lane & 15;
  const int wm = (wave >> 1) * 64, wn = (wave & 1) * 64;
  const int m0 = blockIdx.y * 128, n0 = blockIdx.x * 128;

  const int rsub = lane >> 3;
  const int gc16 = (lane & 7) ^ (rsub & 7);
  const __hip_bfloat16* gA[4];
  const __hip_bfloat16* gB[4];
  __hip_bfloat16* lA[4];
  __hip_bfloat16* lB[4];
#pragma unroll
  for (int i = 0; i < 4; ++i) {
    int c = wave * 4 + i;
    int row = c * 8 + rsub;
    gA[i] = A + (size_t)(m0 + row) * K + gc16 * 8;
    gB[i] = Bt + (size_t)(n0 + row) * K + gc16 * 8;
    lA[i] = Alds + c * 512;
    lB[i] = Blds + c * 512;
  }

  f32x4 acc[4][4] = {};

  for (int k0 = 0; k0 < K; k0 += 64) {
#pragma unroll
    for (int i = 0; i < 4; ++i) {
      GLDS16(gA[i] + k0, lA[i]);
      GLDS16(gB[i] + k0, lB[i]);
    }
    __syncthreads();
#pragma unroll
    for (int kk = 0; kk < 2; ++kk) {
      const int fo = ((kk * 4 + quad) ^ (l15 & 7)) * 8;  // swizzled frag col
      short8 a[4], bfr[4];
#pragma unroll
      for (int mt = 0; mt < 4; ++mt)
        a[mt] = *(const short8*)(Alds + (wm + mt * 16 + l15) * 64 + fo);
#pragma unroll
      for (int nt = 0; nt < 4; ++nt)
        bfr[nt] = *(const short8*)(Blds + (wn + nt * 16 + l15) * 64 + fo);
#pragma unroll
      for (int mt = 0; mt < 4; ++mt)
#pragma unroll
        for (int nt = 0; nt < 4; ++nt)
          acc[mt][nt] = __builtin_amdgcn_mfma_f32_16x16x32_bf16(
              a[mt], bfr[nt], acc[mt][nt], 0, 0, 0);
    }
    __syncthreads();
  }

  if (WVT && n0 >= 2048) {
#pragma unroll
    for (int mt = 0; mt < 4; ++mt)
#pragma unroll
      for (int nt = 0; nt < 4; ++nt) {
        int col = n0 + wn + nt * 16 + l15;
        float bv = bias[col];
        int hv = (col - 2048) >> 6, d = (col - 2048) & 63;
        int row0 = m0 + wm + mt * 16 + quad * 4;
        int bidx = row0 >> 11, s = row0 & 2047;
        uint2 w;
        w.x = pack_bf2(acc[mt][nt][0] + bv, acc[mt][nt][1] + bv);
        w.y = pack_bf2(acc[mt][nt][2] + bv, acc[mt][nt][3] + bv);
        *(uint2*)(vt + ((size_t)(bidx * 16 + hv) * 64 + d) * 2048 + s) = w;
      }
  } else {
#pragma unroll
    for (int mt = 0; mt < 4; ++mt)
#pragma unroll
      for (int nt = 0; nt < 4; ++nt) {
        int col = n0 + wn + nt * 16 + l15;
        float bv = bias[col];
#pragma unroll
        for (int r = 0; r < 4; ++r) {
          int row = m0 + wm + mt * 16 + quad * 4 + r;
          store_out(C + (size_t)row * N + col, acc[mt][nt][r] + bv);
        }
      }
  }
}

// ------------------------------------------------------ flash attention ----
// R8 = R7 body + XCD-pinned block mapping.
// Diagnosis: attn FETCH was 278 MB vs ~48 MB unique -> ~6-8x amplification,
// and 278 MB / 2.85 TB/s ~= the whole kernel time.  The 16 q-blocks sharing
// one (b,h)'s K/V were round-robined across all 8 XCDs, so every private L2
// pulled its own copy of the K/V working set (8 x 32 MB ~= 260 MB ~= FETCH).
// Fix: 1-D grid, decode so xcd = wgid&7 pins 8 whole (b,h) pairs per XCD
// (8 pairs x 0.5 MB K/V = 4 MB = one L2; live tile window ~2.2 MB).
// Load balance unchanged: every block still runs exactly 33 iterations.
__global__ __launch_bounds__(128, 2) void attn_causal(
    const __hip_bfloat16* __restrict__ qkv,
    const __hip_bfloat16* __restrict__ vt,
    __hip_bfloat16* __restrict__ ctx) {
  __shared__ __align__(16) __hip_bfloat16 Klds[2][64 * 64];    // [buf][kpos][d]
  __shared__ __align__(16) __hip_bfloat16 Vlds[2][64 * 64];    // [buf][d][kpos]
  __shared__ __align__(16) __hip_bfloat16 Plds[2][2][16][64];  // [wv][g][q][k]

  const int t = threadIdx.x;
  const int wave = t >> 6, lane = t & 63;
  const int quad = lane >> 4, l15 = lane & 15;

  // ---- XCD-pinned decode: all 16 xb-blocks of a (b,h) pair on one XCD ----
  const int wg = blockIdx.x;            // 0..1023
  const int xcd = wg & 7, loc = wg >> 3;
  const int pair = (xcd << 3) | (loc >> 4);   // 8 pairs per XCD
  const int xb = loc & 15;
  const int b = pair >> 4, h = pair & 15;

  const size_t qbase = (size_t)b * S_ * N3_ + h * HD_;
  const size_t kbase = qbase + D_;
  const size_t vtbase = (size_t)(b * H_ + h) * HD_ * S_;
  const float C2 = 0.18033688f;  // (1/sqrt(64)) * log2(e)

  short8 ones;
#pragma unroll
  for (int j = 0; j < 8; ++j) ones[j] = (short)0x3F80;  // bf16 1.0

  // ---- Q fragments for BOTH sels, hoisted to entry ----
  short8 qf[2][2][2];  // [sel][g][frag]
#pragma unroll
  for (int sel = 0; sel < 2; ++sel) {
    const int qb = sel ? 31 - xb : xb;
#pragma unroll
    for (int g = 0; g < 2; ++g) {
      const int qrow = qb * 64 + wave * 32 + g * 16 + l15;
      qf[sel][g][0] =
          *(const short8*)(qkv + qbase + (size_t)qrow * N3_ + quad * 8);
      qf[sel][g][1] =
          *(const short8*)(qkv + qbase + (size_t)qrow * N3_ + 32 + quad * 8);
    }
  }

  // ---- staging: pre-swizzled global source, linear LDS dest ----
  const int rsub = lane >> 3;               // row within 8-row subtile
  const int swz = ((lane & 7) ^ rsub) * 8;  // swizzled col (elements)
  const __hip_bfloat16* gK[4];              // tile-0 bases
  const __hip_bfloat16* gV[4];
  __hip_bfloat16* lK[4];                    // buf-0 dests
  __hip_bfloat16* lV[4];
#pragma unroll
  for (int i = 0; i < 4; ++i) {
    const int c = wave * 4 + i;             // subtile id (wave-uniform base)
    gK[i] = qkv + kbase + (size_t)(c * 8 + rsub) * N3_ + swz;
    gV[i] = vt + vtbase + (size_t)(c * 8 + rsub) * S_ + swz;
    lK[i] = &Klds[0][c * 512];
    lV[i] = &Vlds[0][c * 512];
  }

  const int fo0 = (quad ^ (l15 & 7)) * 8;        // swizzled frag col, k 0..31
  const int fo1 = ((4 + quad) ^ (l15 & 7)) * 8;  // k 32..63

  // prologue: stage tile 0 -> buf 0
#pragma unroll
  for (int i = 0; i < 4; ++i) {
    GLDS16(gK[i], lK[i]);
    GLDS16(gV[i], lV[i]);
  }
  __syncthreads();
  int cur = 0;

  for (int sel = 0; sel < 2; ++sel) {
    const int qb = sel ? 31 - xb : xb;

    f32x4 o[2][4] = {};                     // O^T accum per group
    float m_r[2] = {-1e30f, -1e30f}, l_r[2] = {0.f, 0.f};

    for (int kb = 0; kb <= qb; ++kb) {
      // ---- prefetch next tile into buf[cur^1] (tile 0 at sel boundary) ----
      if (sel == 0 || kb < qb) {
        const size_t nk = (kb < qb) ? (size_t)(kb + 1) : 0;
        const size_t ko = nk * (size_t)(64 * N3_);
        const size_t vo = nk * 64;
        const int nb = (cur ^ 1) * 4096;
#pragma unroll
        for (int i = 0; i < 4; ++i) {
          GLDS16(gK[i] + ko, lK[i] + nb);
          GLDS16(gV[i] + vo, lV[i] + nb);
        }
      }

      const __hip_bfloat16* Kb = &Klds[cur][0];
      const __hip_bfloat16* Vb = &Vlds[cur][0];

      // ---- K fragments -> regs (conflict-free swizzled b128 reads) ----
      short8 kf[4][2];
#pragma unroll
      for (int nt = 0; nt < 4; ++nt) {
        const __hip_bfloat16* kr = Kb + (nt * 16 + l15) * 64;
        kf[nt][0] = *(const short8*)(kr + fo0);
        kf[nt][1] = *(const short8*)(kr + fo1);
      }

      const bool diag = (kb == qb);
      short8 pB[2][2];
#pragma unroll
      for (int g = 0; g < 2; ++g) {
        f32x4 st[4];
#pragma unroll
        for (int nt = 0; nt < 4; ++nt) {
          f32x4 z = {};
          z = __builtin_amdgcn_mfma_f32_16x16x32_bf16(kf[nt][0], qf[sel][g][0],
                                                      z, 0, 0, 0);
          z = __builtin_amdgcn_mfma_f32_16x16x32_bf16(kf[nt][1], qf[sel][g][1],
                                                      z, 0, 0, 0);
          st[nt] = z;
        }
        if (diag) {  // mask kpos_local > qrow_local
          const int rloc = wave * 32 + g * 16 + l15;
#pragma unroll
          for (int nt = 0; nt < 4; ++nt)
#pragma unroll
            for (int r = 0; r < 4; ++r)
              if (nt * 16 + quad * 4 + r > rloc) st[nt][r] = -1e30f;
        }

        // row max over kpos: in-lane fold + cross-quad shfl
        float tm = st[0][0];
#pragma unroll
        for (int nt = 0; nt < 4; ++nt)
#pragma unroll
          for (int r = 0; r < 4; ++r) tm = fmaxf(tm, st[nt][r]);
        tm = fmaxf(tm, __shfl_xor(tm, 16));
        tm = fmaxf(tm, __shfl_xor(tm, 32));
        const float pm = tm * C2;

        // defer-max: rescale only when the running max grew (P <= 2^8)
        if (!__all(pm - m_r[g] <= 8.0f)) {
          const float mn = fmaxf(m_r[g], pm);
          const float al = __builtin_amdgcn_exp2f(m_r[g] - mn);
          m_r[g] = mn;
          l_r[g] *= al;
#pragma unroll
          for (int dt = 0; dt < 4; ++dt)
#pragma unroll
            for (int r = 0; r < 4; ++r) o[g][dt][r] *= al;
        }
        const float mneg = -m_r[g];

        // P = exp2(fma(st,C2,-m)); pack bf16x4 -> swizzled b64 LDS write
        __hip_bfloat16* prow = &Plds[wave][g][l15][0];
#pragma unroll
        for (int nt = 0; nt < 4; ++nt) {
          float p0 =
              __builtin_amdgcn_exp2f(__builtin_fmaf(st[nt][0], C2, mneg));
          float p1 =
              __builtin_amdgcn_exp2f(__builtin_fmaf(st[nt][1], C2, mneg));
          float p2 =
              __builtin_amdgcn_exp2f(__builtin_fmaf(st[nt][2], C2, mneg));
          float p3 =
              __builtin_amdgcn_exp2f(__builtin_fmaf(st[nt][3], C2, mneg));
          uint2 w;
          w.x = pack_bf2(p0, p1);
          w.y = pack_bf2(p2, p3);
          const int u = nt * 2 + (quad >> 1);  // logical 8-elem unit
          *(uint2*)(prow + ((u ^ (l15 & 7)) * 8 + (quad & 1) * 4)) = w;
        }
        // same-wave round trip (lgkm-ordered, no barrier)
        pB[g][0] = *(const short8*)(prow + fo0);
        pB[g][1] = *(const short8*)(prow + fo1);

        // l += rowsum(P) via ones-MFMA
        f32x4 ps = {};
        ps = __builtin_amdgcn_mfma_f32_16x16x32_bf16(ones, pB[g][0], ps,
                                                     0, 0, 0);
        ps = __builtin_amdgcn_mfma_f32_16x16x32_bf16(ones, pB[g][1], ps,
                                                     0, 0, 0);
        l_r[g] += ps[0];
      }

      // ---- V fragments just before PV (buf[cur] intact under dbuf) ----
      short8 vf[4][2];
#pragma unroll
      for (int dt = 0; dt < 4; ++dt) {
        const __hip_bfloat16* vr = Vb + (dt * 16 + l15) * 64;
        vf[dt][0] = *(const short8*)(vr + fo0);
        vf[dt][1] = *(const short8*)(vr + fo1);
      }
#pragma unroll
      for (int dt = 0; dt < 4; ++dt)
#pragma unroll
        for (int g = 0; g < 2; ++g) {
          o[g][dt] = __builtin_amdgcn_mfma_f32_16x16x32_bf16(
              vf[dt][0], pB[g][0], o[g][dt], 0, 0, 0);
          o[g][dt] = __builtin_amdgcn_mfma_f32_16x16x32_bf16(
              vf[dt][1], pB[g][1], o[g][dt], 0, 0, 0);
        }

      __syncthreads();  // lands prefetch (vmcnt) + guards buf reuse
      cur ^= 1;
    }

    // ---- epilogue: ctx[qrow][d] = O^T/l (no LDS -> no barrier needed) ----
#pragma unroll
    for (int g = 0; g < 2; ++g) {
      const float rl = __builtin_amdgcn_rcpf(l_r[g]);
      const int qrow = qb * 64 + wave * 32 + g * 16 + l15;
      __hip_bfloat16* crow = ctx + ((size_t)b * S_ + qrow) * D_ + h * HD_;
#pragma unroll
      for (int dt = 0; dt < 4; ++dt) {
        uint2 w;
        w.x = pack_bf2(o[g][dt][0] * rl, o[g][dt][1] * rl);
        w.y = pack_bf2(o[g][dt][2] * rl, o[g][dt][3] * rl);
        *(uint2*)(crow + dt * 16 + quad * 4) = w;
      }
    }
  }
}

// --------------------------------------------------------------- launch ----
extern "C" void kernel_launch(void* const* d_in, const int* in_sizes, int n_in,
                              void* d_out, int out_size, void* d_ws,
                              size_t ws_size, hipStream_t stream) {
  const float* x      = (const float*)d_in[0];
  const float* w_qkv  = (const float*)d_in[1];
  const float* b_qkv  = (const float*)d_in[2];
  const float* w_proj = (const float*)d_in[3];
  const float* b_proj = (const float*)d_in[4];
  float* out = (float*)d_out;

  char* ws = (char*)d_ws;
  __hip_bfloat16* xb     = (__hip_bfloat16*)(ws + 0);          // 16 MB
  __hip_bfloat16* wqkvT  = (__hip_bfloat16*)(ws + 16777216);   // 6 MB
  __hip_bfloat16* wprojT = (__hip_bfloat16*)(ws + 23068672);   // 2 MB
  __hip_bfloat16* qkvb   = (__hip_bfloat16*)(ws + 25165824);   // 50.3 MB
  __hip_bfloat16* ctx    = (__hip_bfloat16*)(ws + 75497472);   // 16 MB
  __hip_bfloat16* vt2    = (__hip_bfloat16*)(ws + 91750400);   // 16 MB

  cast_f32_bf16<<<8192, 256, 0, stream>>>(x, xb, M_ * D_);
  transpose_cast<<<dim3(N3_ / 32, D_ / 32), dim3(32, 8), 0, stream>>>(
      w_qkv, wqkvT, D_, N3_);
  transpose_cast<<<dim3(D_ / 32, D_ / 32), dim3(32, 8), 0, stream>>>(
      w_proj, wprojT, D_, D_);

  gemm_bt_bias<__hip_bfloat16, true>
      <<<dim3(N3_ / 128, M_ / 128), 256, 0, stream>>>(
          xb, wqkvT, b_qkv, qkvb, vt2, M_, N3_, D_);

  attn_causal<<<1024, 128, 0, stream>>>(qkvb, vt2, ctx);

  gemm_bt_bias<float, false><<<dim3(D_ / 128, M_ / 128), 256, 0, stream>>>(
      ctx, wprojT, b_proj, out, (__hip_bfloat16*)nullptr, M_, D_, D_);
}

// Round 4
// 274.172 us; speedup vs baseline: 1.1301x; 1.0241x over previous
//
#include <hip/hip_runtime.h>
#include <hip/hip_bf16.h>

typedef __attribute__((ext_vector_type(8))) short short8;
typedef __attribute__((ext_vector_type(4))) float f32x4;
typedef __attribute__((ext_vector_type(16))) float f32x16;

#define B_   4
#define S_   2048
#define D_   1024
#define H_   16
#define HD_  64
#define M_   (B_ * S_)      // 8192
#define N3_  (3 * D_)       // 3072

#define GLDS16(g, l)                                                        \
  __builtin_amdgcn_global_load_lds(                                         \
      (const __attribute__((address_space(1))) void*)(g),                   \
      (__attribute__((address_space(3))) void*)(l), 16, 0, 0)

__device__ __forceinline__ unsigned pack_bf2(float a, float b) {
  union { __hip_bfloat16 h; unsigned short s; } ua, ub;
  ua.h = __float2bfloat16(a);
  ub.h = __float2bfloat16(b);
  return (unsigned)ua.s | ((unsigned)ub.s << 16);
}

// ---------------------------------------------------------------- casts ----
__global__ __launch_bounds__(256) void cast_f32_bf16(
    const float* __restrict__ in, __hip_bfloat16* __restrict__ out, int n) {
  int i = (blockIdx.x * 256 + threadIdx.x) * 4;
  if (i + 3 < n) {
    float4 v = *(const float4*)(in + i);
    union { ushort4 u4; __hip_bfloat16 h[4]; } p;
    p.h[0] = __float2bfloat16(v.x);
    p.h[1] = __float2bfloat16(v.y);
    p.h[2] = __float2bfloat16(v.z);
    p.h[3] = __float2bfloat16(v.w);
    *(ushort4*)(out + i) = p.u4;
  }
}

// in: [rows][cols] fp32 -> out: [cols][rows] bf16
__global__ __launch_bounds__(256) void transpose_cast(
    const float* __restrict__ in, __hip_bfloat16* __restrict__ out,
    int rows, int cols) {
  __shared__ float tile[32][33];
  int bx = blockIdx.x * 32;
  int by = blockIdx.y * 32;
  int tx = threadIdx.x, ty = threadIdx.y;   // (32, 8)
#pragma unroll
  for (int i = 0; i < 4; ++i)
    tile[ty + i * 8][tx] = in[(size_t)(by + ty + i * 8) * cols + bx + tx];
  __syncthreads();
#pragma unroll
  for (int i = 0; i < 4; ++i)
    out[(size_t)(bx + ty + i * 8) * rows + by + tx] =
        __float2bfloat16(tile[tx][ty + i * 8]);
}

// ----------------------------------------------------------------- GEMM ----
__device__ inline void store_out(float* p, float v) { *p = v; }
__device__ inline void store_out(__hip_bfloat16* p, float v) {
  *p = __float2bfloat16(v);
}

template <typename OUT_T, bool WVT>
__global__ __launch_bounds__(256) void gemm_bt_bias(
    const __hip_bfloat16* __restrict__ A, const __hip_bfloat16* __restrict__ Bt,
    const float* __restrict__ bias, OUT_T* __restrict__ C,
    __hip_bfloat16* __restrict__ vt, int M, int N, int K) {
  __shared__ __align__(16) __hip_bfloat16 Alds[128 * 64];
  __shared__ __align__(16) __hip_bfloat16 Blds[128 * 64];
  const int t = threadIdx.x;
  const int wave = t >> 6, lane = t & 63;
  const int quad = lane >> 4, l15 = lane & 15;
  const int wm = (wave >> 1) * 64, wn = (wave & 1) * 64;
  const int m0 = blockIdx.y * 128, n0 = blockIdx.x * 128;

  const int rsub = lane >> 3;
  const int gc16 = (lane & 7) ^ (rsub & 7);
  const __hip_bfloat16* gA[4];
  const __hip_bfloat16* gB[4];
  __hip_bfloat16* lA[4];
  __hip_bfloat16* lB[4];
#pragma unroll
  for (int i = 0; i < 4; ++i) {
    int c = wave * 4 + i;
    int row = c * 8 + rsub;
    gA[i] = A + (size_t)(m0 + row) * K + gc16 * 8;
    gB[i] = Bt + (size_t)(n0 + row) * K + gc16 * 8;
    lA[i] = Alds + c * 512;
    lB[i] = Blds + c * 512;
  }

  f32x4 acc[4][4] = {};

  for (int k0 = 0; k0 < K; k0 += 64) {
#pragma unroll
    for (int i = 0; i < 4; ++i) {
      GLDS16(gA[i] + k0, lA[i]);
      GLDS16(gB[i] + k0, lB[i]);
    }
    __syncthreads();
#pragma unroll
    for (int kk = 0; kk < 2; ++kk) {
      const int fo = ((kk * 4 + quad) ^ (l15 & 7)) * 8;  // swizzled frag col
      short8 a[4], bfr[4];
#pragma unroll
      for (int mt = 0; mt < 4; ++mt)
        a[mt] = *(const short8*)(Alds + (wm + mt * 16 + l15) * 64 + fo);
#pragma unroll
      for (int nt = 0; nt < 4; ++nt)
        bfr[nt] = *(const short8*)(Blds + (wn + nt * 16 + l15) * 64 + fo);
#pragma unroll
      for (int mt = 0; mt < 4; ++mt)
#pragma unroll
        for (int nt = 0; nt < 4; ++nt)
          acc[mt][nt] = __builtin_amdgcn_mfma_f32_16x16x32_bf16(
              a[mt], bfr[nt], acc[mt][nt], 0, 0, 0);
    }
    __syncthreads();
  }

  if (WVT && n0 >= 2048) {
#pragma unroll
    for (int mt = 0; mt < 4; ++mt)
#pragma unroll
      for (int nt = 0; nt < 4; ++nt) {
        int col = n0 + wn + nt * 16 + l15;
        float bv = bias[col];
        int hv = (col - 2048) >> 6, d = (col - 2048) & 63;
        int row0 = m0 + wm + mt * 16 + quad * 4;
        int bidx = row0 >> 11, s = row0 & 2047;
        uint2 w;
        w.x = pack_bf2(acc[mt][nt][0] + bv, acc[mt][nt][1] + bv);
        w.y = pack_bf2(acc[mt][nt][2] + bv, acc[mt][nt][3] + bv);
        *(uint2*)(vt + ((size_t)(bidx * 16 + hv) * 64 + d) * 2048 + s) = w;
      }
  } else {
#pragma unroll
    for (int mt = 0; mt < 4; ++mt)
#pragma unroll
      for (int nt = 0; nt < 4; ++nt) {
        int col = n0 + wn + nt * 16 + l15;
        float bv = bias[col];
#pragma unroll
        for (int r = 0; r < 4; ++r) {
          int row = m0 + wm + mt * 16 + quad * 4 + r;
          store_out(C + (size_t)row * N + col, acc[mt][nt][r] + bv);
        }
      }
  }
}

// ------------------------------------------------------ flash attention ----
// R9 = R8 grid/pinning/staging + 32x32x16 MFMA => in-register softmax.
// Diagnosis (R8): latency-bound, 6.8K cyc/iter vs ~700 cyc MFMA work; chain
// dominated by P LDS round-trip + 2 shfls + rowsum-MFMA dependency forced by
// the 16x16 layout.  32x32x16 C/D layout (col=lane&31 = qrow, row = kpos =
// (reg&3)+8*(reg>>2)+4*(lane>>5)) gives each lane a full P-row half for ONE
// qrow: row-max = in-lane fold + one shfl_xor(32); P->PV B-fragment needs
// only same-qrow shfl_xor(32) exchanges (8 dwords) -- no Plds, no lgkm stall.
// LDS 40->32 KB.  Grid, pairing, XCD pinning, GLDS16 dbuf unchanged.
__global__ __launch_bounds__(128, 2) void attn_causal(
    const __hip_bfloat16* __restrict__ qkv,
    const __hip_bfloat16* __restrict__ vt,
    __hip_bfloat16* __restrict__ ctx) {
  __shared__ __align__(16) __hip_bfloat16 Klds[2][64 * 64];  // [buf][kpos][d]
  __shared__ __align__(16) __hip_bfloat16 Vlds[2][64 * 64];  // [buf][d][kpos]

  const int t = threadIdx.x;
  const int wave = t >> 6, lane = t & 63;
  const int r31 = lane & 31, a5 = lane >> 5;   // qrow-in-strip, kpos-half
  const int xr = r31 & 7;                      // swizzle row phase

  // ---- XCD-pinned decode: all 16 xb-blocks of a (b,h) pair on one XCD ----
  const int wg = blockIdx.x;                  // 0..1023
  const int xcd = wg & 7, loc = wg >> 3;
  const int pair = (xcd << 3) | (loc >> 4);   // 8 pairs per XCD
  const int xb = loc & 15;
  const int b = pair >> 4, h = pair & 15;

  const size_t qbase = (size_t)b * S_ * N3_ + h * HD_;
  const size_t kbase = qbase + D_;
  const size_t vtbase = (size_t)(b * H_ + h) * HD_ * S_;
  const float C2 = 0.18033688f;  // (1/sqrt(64)) * log2(e)

  short8 ones;
#pragma unroll
  for (int j = 0; j < 8; ++j) ones[j] = (short)0x3F80;  // bf16 1.0

  // ---- staging: pre-swizzled global source, linear LDS dest ----
  const int rsub = lane >> 3;               // row within 8-row subtile
  const int swz = ((lane & 7) ^ rsub) * 8;  // swizzled col (elements)
  const __hip_bfloat16* gK[4];              // tile-0 bases
  const __hip_bfloat16* gV[4];
  __hip_bfloat16* lK[4];
  __hip_bfloat16* lV[4];
#pragma unroll
  for (int i = 0; i < 4; ++i) {
    const int c = wave * 4 + i;             // subtile id (wave-uniform base)
    gK[i] = qkv + kbase + (size_t)(c * 8 + rsub) * N3_ + swz;
    gV[i] = vt + vtbase + (size_t)(c * 8 + rsub) * S_ + swz;
    lK[i] = &Klds[0][c * 512];
    lV[i] = &Vlds[0][c * 512];
  }

  // prologue: stage tile 0 -> buf 0
#pragma unroll
  for (int i = 0; i < 4; ++i) {
    GLDS16(gK[i], lK[i]);
    GLDS16(gV[i], lV[i]);
  }
  __syncthreads();
  int cur = 0;

// pack own p-pair dwords + same-qrow cross-half exchange -> PV B-fragment.
// B-frag k-slot j (=lane-half*8+j within 16-k chunk): a=0 lanes need kpos
// {0..7} = own A-group + partner A-group; a=1 lanes need {8..15} = partner
// B-group + own B-group.  shfl_xor(32) swaps between halves of same qrow.
#define MKFRAG(sv, Bofs, OUT)                                          \
  {                                                                    \
    unsigned dA0 = pack_bf2(sv[Bofs + 0], sv[Bofs + 1]);               \
    unsigned dA1 = pack_bf2(sv[Bofs + 2], sv[Bofs + 3]);               \
    unsigned dB0 = pack_bf2(sv[Bofs + 4], sv[Bofs + 5]);               \
    unsigned dB1 = pack_bf2(sv[Bofs + 6], sv[Bofs + 7]);               \
    unsigned c0 = (unsigned)__shfl_xor((int)(a5 ? dA0 : dB0), 32);     \
    unsigned c1 = (unsigned)__shfl_xor((int)(a5 ? dA1 : dB1), 32);     \
    union { unsigned u[4]; short8 s8; } pu;                            \
    pu.u[0] = a5 ? c0 : dA0;                                           \
    pu.u[1] = a5 ? c1 : dA1;                                           \
    pu.u[2] = a5 ? dB0 : c0;                                           \
    pu.u[3] = a5 ? dB1 : c1;                                           \
    OUT = pu.s8;                                                       \
  }

  for (int sel = 0; sel < 2; ++sel) {
    const int qb = sel ? 31 - xb : xb;
    const int qrow = qb * 64 + wave * 32 + r31;   // this lane's q-row
    const int rlq = wave * 32 + r31;              // row within 64-block

    // Q fragments: B-operand, k = a5*8+j within each 16-d chunk
    short8 qf[4];
#pragma unroll
    for (int dc = 0; dc < 4; ++dc)
      qf[dc] = *(const short8*)(qkv + qbase + (size_t)qrow * N3_ +
                                dc * 16 + a5 * 8);

    f32x16 o0 = {}, o1 = {};                  // O^T, d-halves 0-31 / 32-63
    float m_r = -1e30f, l_r = 0.f;

    for (int kb = 0; kb <= qb; ++kb) {
      // ---- prefetch next tile into buf[cur^1] (tile 0 at sel boundary) ----
      if (sel == 0 || kb < qb) {
        const size_t nk = (kb < qb) ? (size_t)(kb + 1) : 0;
        const size_t ko = nk * (size_t)(64 * N3_);
        const size_t vo = nk * 64;
        const int nb = (cur ^ 1) * 4096;
#pragma unroll
        for (int i = 0; i < 4; ++i) {
          GLDS16(gK[i] + ko, lK[i] + nb);
          GLDS16(gV[i] + vo, lV[i] + nb);
        }
      }

      const __hip_bfloat16* Kb = &Klds[cur][0];
      const __hip_bfloat16* Vb = &Vlds[cur][0];

      // ---- K A-frags: row kpos = h*32+r31, k = d-chunk (swizzled b128) ----
      short8 kf0[4], kf1[4];
#pragma unroll
      for (int dc = 0; dc < 4; ++dc) {
        const int u = ((dc * 2 + a5) ^ xr) * 8;
        kf0[dc] = *(const short8*)(Kb + r31 * 64 + u);
        kf1[dc] = *(const short8*)(Kb + (32 + r31) * 64 + u);
      }

      // ---- QK^T: st[kpos][qrow], two kpos-half tiles ----
      f32x16 s0 = {}, s1 = {};
#pragma unroll
      for (int dc = 0; dc < 4; ++dc) {
        s0 = __builtin_amdgcn_mfma_f32_32x32x16_bf16(kf0[dc], qf[dc], s0,
                                                     0, 0, 0);
        s1 = __builtin_amdgcn_mfma_f32_32x32x16_bf16(kf1[dc], qf[dc], s1,
                                                     0, 0, 0);
      }

      if (kb == qb) {  // causal mask: kpos_local > qrow_local
#pragma unroll
        for (int reg = 0; reg < 16; ++reg) {
          const int kl = (reg & 3) + 8 * (reg >> 2) + 4 * a5;
          if (kl > rlq) s0[reg] = -1e30f;
          if (kl + 32 > rlq) s1[reg] = -1e30f;
        }
      }

      // ---- row max: in-lane fold + one cross-half exchange ----
      float tm = s0[0];
#pragma unroll
      for (int reg = 1; reg < 16; ++reg) tm = fmaxf(tm, s0[reg]);
#pragma unroll
      for (int reg = 0; reg < 16; ++reg) tm = fmaxf(tm, s1[reg]);
      tm = fmaxf(tm, __shfl_xor(tm, 32));
      const float pm = tm * C2;

      // defer-max: rescale only when the running max grew (P <= 2^8)
      if (!__all(pm - m_r <= 8.0f)) {
        const float mn = fmaxf(m_r, pm);
        const float al = __builtin_amdgcn_exp2f(m_r - mn);
        m_r = mn;
        l_r *= al;
        o0 *= al;
        o1 *= al;
      }
      const float mneg = -m_r;

      // ---- P = exp2(fma(st,C2,-m)) in place ----
#pragma unroll
      for (int reg = 0; reg < 16; ++reg) {
        s0[reg] = __builtin_amdgcn_exp2f(__builtin_fmaf(s0[reg], C2, mneg));
        s1[reg] = __builtin_amdgcn_exp2f(__builtin_fmaf(s1[reg], C2, mneg));
      }

      // ---- pack + exchange -> 4 PV B-fragments (16 kpos each) ----
      short8 pf[4];
      MKFRAG(s0, 0, pf[0]);
      MKFRAG(s0, 8, pf[1]);
      MKFRAG(s1, 0, pf[2]);
      MKFRAG(s1, 8, pf[3]);

      // ---- rowsum via ones-MFMA (colsum of P per qrow) ----
      f32x16 ps = {};
#pragma unroll
      for (int kc = 0; kc < 4; ++kc)
        ps = __builtin_amdgcn_mfma_f32_32x32x16_bf16(ones, pf[kc], ps,
                                                     0, 0, 0);
      l_r += ps[0];

      // ---- PV: A = V^T[d][k] frags, B = pf; accumulate O^T ----
#pragma unroll
      for (int kc = 0; kc < 4; ++kc) {
        const int u = ((kc * 2 + a5) ^ xr) * 8;
        short8 v0 = *(const short8*)(Vb + r31 * 64 + u);
        short8 v1 = *(const short8*)(Vb + (32 + r31) * 64 + u);
        o0 = __builtin_amdgcn_mfma_f32_32x32x16_bf16(v0, pf[kc], o0, 0, 0, 0);
        o1 = __builtin_amdgcn_mfma_f32_32x32x16_bf16(v1, pf[kc], o1, 0, 0, 0);
      }

      __syncthreads();  // lands prefetch (vmcnt) + guards buf reuse
      cur ^= 1;
    }

    // ---- epilogue: ctx[qrow][d]; lane holds d = 32*dh + 8*q2 + 4*a5 + rr --
    const float rl = __builtin_amdgcn_rcpf(l_r);
    __hip_bfloat16* crow = ctx + ((size_t)b * S_ + qrow) * D_ + h * HD_;
#pragma unroll
    for (int q2 = 0; q2 < 4; ++q2) {
      uint2 w;
      w.x = pack_bf2(o0[q2 * 4 + 0] * rl, o0[q2 * 4 + 1] * rl);
      w.y = pack_bf2(o0[q2 * 4 + 2] * rl, o0[q2 * 4 + 3] * rl);
      *(uint2*)(crow + 8 * q2 + 4 * a5) = w;
      w.x = pack_bf2(o1[q2 * 4 + 0] * rl, o1[q2 * 4 + 1] * rl);
      w.y = pack_bf2(o1[q2 * 4 + 2] * rl, o1[q2 * 4 + 3] * rl);
      *(uint2*)(crow + 32 + 8 * q2 + 4 * a5) = w;
    }
  }
#undef MKFRAG
}

// --------------------------------------------------------------- launch ----
extern "C" void kernel_launch(void* const* d_in, const int* in_sizes, int n_in,
                              void* d_out, int out_size, void* d_ws,
                              size_t ws_size, hipStream_t stream) {
  const float* x      = (const float*)d_in[0];
  const float* w_qkv  = (const float*)d_in[1];
  const float* b_qkv  = (const float*)d_in[2];
  const float* w_proj = (const float*)d_in[3];
  const float* b_proj = (const float*)d_in[4];
  float* out = (float*)d_out;

  char* ws = (char*)d_ws;
  __hip_bfloat16* xb     = (__hip_bfloat16*)(ws + 0);          // 16 MB
  __hip_bfloat16* wqkvT  = (__hip_bfloat16*)(ws + 16777216);   // 6 MB
  __hip_bfloat16* wprojT = (__hip_bfloat16*)(ws + 23068672);   // 2 MB
  __hip_bfloat16* qkvb   = (__hip_bfloat16*)(ws + 25165824);   // 50.3 MB
  __hip_bfloat16* ctx    = (__hip_bfloat16*)(ws + 75497472);   // 16 MB
  __hip_bfloat16* vt2    = (__hip_bfloat16*)(ws + 91750400);   // 16 MB

  cast_f32_bf16<<<8192, 256, 0, stream>>>(x, xb, M_ * D_);
  transpose_cast<<<dim3(N3_ / 32, D_ / 32), dim3(32, 8), 0, stream>>>(
      w_qkv, wqkvT, D_, N3_);
  transpose_cast<<<dim3(D_ / 32, D_ / 32), dim3(32, 8), 0, stream>>>(
      w_proj, wprojT, D_, D_);

  gemm_bt_bias<__hip_bfloat16, true>
      <<<dim3(N3_ / 128, M_ / 128), 256, 0, stream>>>(
          xb, wqkvT, b_qkv, qkvb, vt2, M_, N3_, D_);

  attn_causal<<<1024, 128, 0, stream>>>(qkvb, vt2, ctx);

  gemm_bt_bias<float, false><<<dim3(D_ / 128, M_ / 128), 256, 0, stream>>>(
      ctx, wprojT, b_proj, out, (__hip_bfloat16*)nullptr, M_, D_, D_);
}

// Round 5
// 266.831 us; speedup vs baseline: 1.1612x; 1.0275x over previous
//
#include <hip/hip_runtime.h>
#include <hip/hip_bf16.h>

typedef __attribute__((ext_vector_type(8))) short short8;
typedef __attribute__((ext_vector_type(4))) float f32x4;
typedef __attribute__((ext_vector_type(16))) float f32x16;

#define B_   4
#define S_   2048
#define D_   1024
#define H_   16
#define HD_  64
#define M_   (B_ * S_)      // 8192
#define N3_  (3 * D_)       // 3072

#define GLDS16(g, l)                                                        \
  __builtin_amdgcn_global_load_lds(                                         \
      (const __attribute__((address_space(1))) void*)(g),                   \
      (__attribute__((address_space(3))) void*)(l), 16, 0, 0)

__device__ __forceinline__ unsigned pack_bf2(float a, float b) {
  union { __hip_bfloat16 h; unsigned short s; } ua, ub;
  ua.h = __float2bfloat16(a);
  ub.h = __float2bfloat16(b);
  return (unsigned)ua.s | ((unsigned)ub.s << 16);
}

// ---------------------------------------------------------------- casts ----
__global__ __launch_bounds__(256) void cast_f32_bf16(
    const float* __restrict__ in, __hip_bfloat16* __restrict__ out, int n) {
  int i = (blockIdx.x * 256 + threadIdx.x) * 4;
  if (i + 3 < n) {
    float4 v = *(const float4*)(in + i);
    union { ushort4 u4; __hip_bfloat16 h[4]; } p;
    p.h[0] = __float2bfloat16(v.x);
    p.h[1] = __float2bfloat16(v.y);
    p.h[2] = __float2bfloat16(v.z);
    p.h[3] = __float2bfloat16(v.w);
    *(ushort4*)(out + i) = p.u4;
  }
}

// in: [rows][cols] fp32 -> out: [cols][rows] bf16
__global__ __launch_bounds__(256) void transpose_cast(
    const float* __restrict__ in, __hip_bfloat16* __restrict__ out,
    int rows, int cols) {
  __shared__ float tile[32][33];
  int bx = blockIdx.x * 32;
  int by = blockIdx.y * 32;
  int tx = threadIdx.x, ty = threadIdx.y;   // (32, 8)
#pragma unroll
  for (int i = 0; i < 4; ++i)
    tile[ty + i * 8][tx] = in[(size_t)(by + ty + i * 8) * cols + bx + tx];
  __syncthreads();
#pragma unroll
  for (int i = 0; i < 4; ++i)
    out[(size_t)(bx + ty + i * 8) * rows + by + tx] =
        __float2bfloat16(tile[tx][ty + i * 8]);
}

// ----------------------------------------------------------------- GEMM ----
__device__ inline void store_out(float* p, float v) { *p = v; }
__device__ inline void store_out(__hip_bfloat16* p, float v) {
  *p = __float2bfloat16(v);
}

template <typename OUT_T, bool WVT>
__global__ __launch_bounds__(256) void gemm_bt_bias(
    const __hip_bfloat16* __restrict__ A, const __hip_bfloat16* __restrict__ Bt,
    const float* __restrict__ bias, OUT_T* __restrict__ C,
    __hip_bfloat16* __restrict__ vt, int M, int N, int K) {
  __shared__ __align__(16) __hip_bfloat16 Alds[128 * 64];
  __shared__ __align__(16) __hip_bfloat16 Blds[128 * 64];
  const int t = threadIdx.x;
  const int wave = t >> 6, lane = t & 63;
  const int quad = lane >> 4, l15 = lane & 15;
  const int wm = (wave >> 1) * 64, wn = (wave & 1) * 64;
  const int m0 = blockIdx.y * 128, n0 = blockIdx.x * 128;

  const int rsub = lane >> 3;
  const int gc16 = (lane & 7) ^ (rsub & 7);
  const __hip_bfloat16* gA[4];
  const __hip_bfloat16* gB[4];
  __hip_bfloat16* lA[4];
  __hip_bfloat16* lB[4];
#pragma unroll
  for (int i = 0; i < 4; ++i) {
    int c = wave * 4 + i;
    int row = c * 8 + rsub;
    gA[i] = A + (size_t)(m0 + row) * K + gc16 * 8;
    gB[i] = Bt + (size_t)(n0 + row) * K + gc16 * 8;
    lA[i] = Alds + c * 512;
    lB[i] = Blds + c * 512;
  }

  f32x4 acc[4][4] = {};

  for (int k0 = 0; k0 < K; k0 += 64) {
#pragma unroll
    for (int i = 0; i < 4; ++i) {
      GLDS16(gA[i] + k0, lA[i]);
      GLDS16(gB[i] + k0, lB[i]);
    }
    __syncthreads();
#pragma unroll
    for (int kk = 0; kk < 2; ++kk) {
      const int fo = ((kk * 4 + quad) ^ (l15 & 7)) * 8;  // swizzled frag col
      short8 a[4], bfr[4];
#pragma unroll
      for (int mt = 0; mt < 4; ++mt)
        a[mt] = *(const short8*)(Alds + (wm + mt * 16 + l15) * 64 + fo);
#pragma unroll
      for (int nt = 0; nt < 4; ++nt)
        bfr[nt] = *(const short8*)(Blds + (wn + nt * 16 + l15) * 64 + fo);
#pragma unroll
      for (int mt = 0; mt < 4; ++mt)
#pragma unroll
        for (int nt = 0; nt < 4; ++nt)
          acc[mt][nt] = __builtin_amdgcn_mfma_f32_16x16x32_bf16(
              a[mt], bfr[nt], acc[mt][nt], 0, 0, 0);
    }
    __syncthreads();
  }

  if (WVT && n0 >= 2048) {
#pragma unroll
    for (int mt = 0; mt < 4; ++mt)
#pragma unroll
      for (int nt = 0; nt < 4; ++nt) {
        int col = n0 + wn + nt * 16 + l15;
        float bv = bias[col];
        int hv = (col - 2048) >> 6, d = (col - 2048) & 63;
        int row0 = m0 + wm + mt * 16 + quad * 4;
        int bidx = row0 >> 11, s = row0 & 2047;
        uint2 w;
        w.x = pack_bf2(acc[mt][nt][0] + bv, acc[mt][nt][1] + bv);
        w.y = pack_bf2(acc[mt][nt][2] + bv, acc[mt][nt][3] + bv);
        *(uint2*)(vt + ((size_t)(bidx * 16 + hv) * 64 + d) * 2048 + s) = w;
      }
  } else {
#pragma unroll
    for (int mt = 0; mt < 4; ++mt)
#pragma unroll
      for (int nt = 0; nt < 4; ++nt) {
        int col = n0 + wn + nt * 16 + l15;
        float bv = bias[col];
#pragma unroll
        for (int r = 0; r < 4; ++r) {
          int row = m0 + wm + mt * 16 + quad * 4 + r;
          store_out(C + (size_t)row * N + col, acc[mt][nt][r] + bv);
        }
      }
  }
}

// ------------------------------------------------------ flash attention ----
// R10 = R9 + split-K within the block: 256 thr / 4 waves share ONE K/V
// stream.  Diagnosis (R9): grid-capped at 8 waves/CU (25%) -- every pipe
// <36%, latency-bound, and the only lever left is MORE WAVES per LDS
// stream.  Wave (kh,rh): q-rows rh*32..+32, kpos-half kh*32..+32 of the
// shared 64x64 tile; independent online-softmax per wave; kh=1 partials
// (m,l,O) merged into kh=0 at sel end via LDS scratch (= consumed dbuf).
// 4096 waves = 16/CU = 50% occupancy cap (was 25%).  Per-wave chain also
// halves; rowsum now in-lane f32 tree (drops 4 ones-MFMA deps); tree-fmax;
// diag's fully-masked wave (kh=1,rh=0) skips compute.
__global__ __launch_bounds__(256, 4) void attn_causal(
    const __hip_bfloat16* __restrict__ qkv,
    const __hip_bfloat16* __restrict__ vt,
    __hip_bfloat16* __restrict__ ctx) {
  __shared__ __align__(16) __hip_bfloat16 Klds[2][64 * 64];  // [buf][kpos][d]
  __shared__ __align__(16) __hip_bfloat16 Vlds[2][64 * 64];  // [buf][d][kpos]
  __shared__ float mlbuf[64][2];                             // kh=1 (m,l)

  const int t = threadIdx.x;
  const int wave = t >> 6, lane = t & 63;
  const int kh = wave >> 1, rh = wave & 1;     // kpos-half, row-half
  const int r31 = lane & 31, a5 = lane >> 5;
  const int xr = r31 & 7;                      // swizzle row phase

  // ---- XCD-pinned decode: all 16 xb-blocks of a (b,h) pair on one XCD ----
  const int wg = blockIdx.x;                  // 0..1023
  const int xcd = wg & 7, loc = wg >> 3;
  const int pair = (xcd << 3) | (loc >> 4);   // 8 pairs per XCD
  const int xb = loc & 15;
  const int b = pair >> 4, h = pair & 15;

  const size_t qbase = (size_t)b * S_ * N3_ + h * HD_;
  const size_t kbase = qbase + D_;
  const size_t vtbase = (size_t)(b * H_ + h) * HD_ * S_;
  const float C2 = 0.18033688f;  // (1/sqrt(64)) * log2(e)

  // ---- staging: pre-swizzled global source, linear LDS dest ----
  const int rsub = lane >> 3;               // row within 8-row subtile
  const int swz = ((lane & 7) ^ rsub) * 8;  // swizzled col (elements)
  const __hip_bfloat16* gK[2];              // tile-0 bases
  const __hip_bfloat16* gV[2];
  __hip_bfloat16* lK[2];
  __hip_bfloat16* lV[2];
#pragma unroll
  for (int i = 0; i < 2; ++i) {
    const int c = wave * 2 + i;             // subtile id (wave-uniform base)
    gK[i] = qkv + kbase + (size_t)(c * 8 + rsub) * N3_ + swz;
    gV[i] = vt + vtbase + (size_t)(c * 8 + rsub) * S_ + swz;
    lK[i] = &Klds[0][c * 512];
    lV[i] = &Vlds[0][c * 512];
  }

  // prologue: stage tile 0 -> buf 0
#pragma unroll
  for (int i = 0; i < 2; ++i) {
    GLDS16(gK[i], lK[i]);
    GLDS16(gV[i], lV[i]);
  }
  __syncthreads();
  int cur = 0;

// pack own p-pair dwords + same-qrow cross-half exchange -> PV B-fragment.
#define MKFRAG(sv, Bofs, OUT)                                          \
  {                                                                    \
    unsigned dA0 = pack_bf2(sv[Bofs + 0], sv[Bofs + 1]);               \
    unsigned dA1 = pack_bf2(sv[Bofs + 2], sv[Bofs + 3]);               \
    unsigned dB0 = pack_bf2(sv[Bofs + 4], sv[Bofs + 5]);               \
    unsigned dB1 = pack_bf2(sv[Bofs + 6], sv[Bofs + 7]);               \
    unsigned c0 = (unsigned)__shfl_xor((int)(a5 ? dA0 : dB0), 32);     \
    unsigned c1 = (unsigned)__shfl_xor((int)(a5 ? dA1 : dB1), 32);     \
    union { unsigned u[4]; short8 s8; } pu;                            \
    pu.u[0] = a5 ? c0 : dA0;                                           \
    pu.u[1] = a5 ? c1 : dA1;                                           \
    pu.u[2] = a5 ? dB0 : c0;                                           \
    pu.u[3] = a5 ? dB1 : c1;                                           \
    OUT = pu.s8;                                                       \
  }

  for (int sel = 0; sel < 2; ++sel) {
    const int qb = sel ? 31 - xb : xb;
    const int qrow = qb * 64 + rh * 32 + r31;   // this lane's q-row

    // Q fragments: B-operand, k = a5*8+j within each 16-d chunk
    short8 qf[4];
#pragma unroll
    for (int dc = 0; dc < 4; ++dc)
      qf[dc] = *(const short8*)(qkv + qbase + (size_t)qrow * N3_ +
                                dc * 16 + a5 * 8);

    f32x16 o0 = {}, o1 = {};                  // O^T, d-halves 0-31 / 32-63
    float m_r = -1e30f, l_r = 0.f;

    for (int kb = 0; kb <= qb; ++kb) {
      // ---- prefetch next tile into buf[cur^1] (tile 0 at sel boundary) ----
      if (sel == 0 || kb < qb) {
        const size_t nk = (kb < qb) ? (size_t)(kb + 1) : 0;
        const size_t ko = nk * (size_t)(64 * N3_);
        const size_t vo = nk * 64;
        const int nb = (cur ^ 1) * 4096;
#pragma unroll
        for (int i = 0; i < 2; ++i) {
          GLDS16(gK[i] + ko, lK[i] + nb);
          GLDS16(gV[i] + vo, lV[i] + nb);
        }
      }

      const bool diag = (kb == qb);
      if (!(diag && kh == 1 && rh == 0)) {   // that wave is fully masked
        const __hip_bfloat16* Kb = &Klds[cur][0];
        const __hip_bfloat16* Vb = &Vlds[cur][0];

        // ---- K A-frags: row kpos = kh*32+r31 (swizzled b128) ----
        short8 kf[4];
#pragma unroll
        for (int dc = 0; dc < 4; ++dc)
          kf[dc] = *(const short8*)(Kb + (kh * 32 + r31) * 64 +
                                    (((dc * 2 + a5) ^ xr) * 8));

        // ---- QK^T: s[kpos-half][qrow] ----
        f32x16 s = {};
#pragma unroll
        for (int dc = 0; dc < 4; ++dc)
          s = __builtin_amdgcn_mfma_f32_32x32x16_bf16(kf[dc], qf[dc], s,
                                                      0, 0, 0);

        if (diag && kh == rh) {  // partial mask (kin > r31)
#pragma unroll
          for (int reg = 0; reg < 16; ++reg) {
            const int kin = (reg & 3) + 8 * (reg >> 2) + 4 * a5;
            if (kin > r31) s[reg] = -1e30f;
          }
        }

        // ---- row max: depth-4 tree + one cross-half exchange ----
        float t8[8];
#pragma unroll
        for (int i = 0; i < 8; ++i) t8[i] = fmaxf(s[i], s[i + 8]);
#pragma unroll
        for (int st = 4; st >= 1; st >>= 1)
#pragma unroll
          for (int i = 0; i < 4; ++i)
            if (i < st) t8[i] = fmaxf(t8[i], t8[i + st]);
        float tm = fmaxf(t8[0], __shfl_xor(t8[0], 32));
        const float pm = tm * C2;

        // defer-max: rescale only when the running max grew (P <= 2^8)
        if (!__all(pm - m_r <= 8.0f)) {
          const float mn = fmaxf(m_r, pm);
          const float al = __builtin_amdgcn_exp2f(m_r - mn);
          m_r = mn;
          l_r *= al;
          o0 *= al;
          o1 *= al;
        }
        const float mneg = -m_r;

        // ---- P = exp2(fma(s,C2,-m)) in place ----
#pragma unroll
        for (int reg = 0; reg < 16; ++reg)
          s[reg] = __builtin_amdgcn_exp2f(__builtin_fmaf(s[reg], C2, mneg));

        // ---- rowsum: in-lane f32 tree + cross-half add ----
        float u8[8];
#pragma unroll
        for (int i = 0; i < 8; ++i) u8[i] = s[i] + s[i + 8];
#pragma unroll
        for (int st = 4; st >= 1; st >>= 1)
#pragma unroll
          for (int i = 0; i < 4; ++i)
            if (i < st) u8[i] = u8[i] + u8[i + st];
        l_r += u8[0] + __shfl_xor(u8[0], 32);

        // ---- pack + exchange -> 2 PV B-fragments (16 kpos each) ----
        short8 pf[2];
        MKFRAG(s, 0, pf[0]);
        MKFRAG(s, 8, pf[1]);

        // ---- PV: A = V^T[d][kpos] frags, B = pf; accumulate O^T ----
#pragma unroll
        for (int kc = 0; kc < 2; ++kc) {
          const int u = (((kh * 2 + kc) * 2 + a5) ^ xr) * 8;
          short8 v0 = *(const short8*)(Vb + r31 * 64 + u);
          short8 v1 = *(const short8*)(Vb + (32 + r31) * 64 + u);
          o0 = __builtin_amdgcn_mfma_f32_32x32x16_bf16(v0, pf[kc], o0,
                                                       0, 0, 0);
          o1 = __builtin_amdgcn_mfma_f32_32x32x16_bf16(v1, pf[kc], o1,
                                                       0, 0, 0);
        }
      }

      __syncthreads();  // lands prefetch (vmcnt) + guards buf reuse
      cur ^= 1;
    }

    // ---- merge kh=1 partial into kh=0 via LDS scratch (= consumed buf) ----
    // scratch: rows 0-31 O_b in Klds[cur^1], rows 32-63 in Vlds[cur^1] (f32)
    if (kh == 1) {
      if (a5 == 0) {
        mlbuf[rh * 32 + r31][0] = m_r;
        mlbuf[rh * 32 + r31][1] = l_r;
      }
      float* obase =
          (rh ? (float*)&Vlds[cur ^ 1][0] : (float*)&Klds[cur ^ 1][0]) +
          r31 * 64;
#pragma unroll
      for (int q2 = 0; q2 < 4; ++q2) {
        float4 w0 = {o0[q2 * 4 + 0], o0[q2 * 4 + 1],
                     o0[q2 * 4 + 2], o0[q2 * 4 + 3]};
        *(float4*)(obase + 8 * q2 + 4 * a5) = w0;
        float4 w1 = {o1[q2 * 4 + 0], o1[q2 * 4 + 1],
                     o1[q2 * 4 + 2], o1[q2 * 4 + 3]};
        *(float4*)(obase + 32 + 8 * q2 + 4 * a5) = w1;
      }
    }
    __syncthreads();
    if (kh == 0) {
      const float m_b = mlbuf[rh * 32 + r31][0];
      const float l_b = mlbuf[rh * 32 + r31][1];
      const float mn = fmaxf(m_r, m_b);
      const float aa = __builtin_amdgcn_exp2f(m_r - mn);
      const float ab = __builtin_amdgcn_exp2f(m_b - mn);
      const float lt = l_r * aa + l_b * ab;
      const float rl = __builtin_amdgcn_rcpf(lt);
      const float fa = aa * rl, fb = ab * rl;
      const float* obase =
          (rh ? (const float*)&Vlds[cur ^ 1][0]
              : (const float*)&Klds[cur ^ 1][0]) + r31 * 64;
      __hip_bfloat16* crow = ctx + ((size_t)b * S_ + qrow) * D_ + h * HD_;
#pragma unroll
      for (int q2 = 0; q2 < 4; ++q2) {
        float4 vb0 = *(const float4*)(obase + 8 * q2 + 4 * a5);
        float4 vb1 = *(const float4*)(obase + 32 + 8 * q2 + 4 * a5);
        uint2 w;
        w.x = pack_bf2(o0[q2 * 4 + 0] * fa + vb0.x * fb,
                       o0[q2 * 4 + 1] * fa + vb0.y * fb);
        w.y = pack_bf2(o0[q2 * 4 + 2] * fa + vb0.z * fb,
                       o0[q2 * 4 + 3] * fa + vb0.w * fb);
        *(uint2*)(crow + 8 * q2 + 4 * a5) = w;
        w.x = pack_bf2(o1[q2 * 4 + 0] * fa + vb1.x * fb,
                       o1[q2 * 4 + 1] * fa + vb1.y * fb);
        w.y = pack_bf2(o1[q2 * 4 + 2] * fa + vb1.z * fb,
                       o1[q2 * 4 + 3] * fa + vb1.w * fb);
        *(uint2*)(crow + 32 + 8 * q2 + 4 * a5) = w;
      }
    }
    __syncthreads();  // protect scratch from next sel's prefetch
  }
#undef MKFRAG
}

// --------------------------------------------------------------- launch ----
extern "C" void kernel_launch(void* const* d_in, const int* in_sizes, int n_in,
                              void* d_out, int out_size, void* d_ws,
                              size_t ws_size, hipStream_t stream) {
  const float* x      = (const float*)d_in[0];
  const float* w_qkv  = (const float*)d_in[1];
  const float* b_qkv  = (const float*)d_in[2];
  const float* w_proj = (const float*)d_in[3];
  const float* b_proj = (const float*)d_in[4];
  float* out = (float*)d_out;

  char* ws = (char*)d_ws;
  __hip_bfloat16* xb     = (__hip_bfloat16*)(ws + 0);          // 16 MB
  __hip_bfloat16* wqkvT  = (__hip_bfloat16*)(ws + 16777216);   // 6 MB
  __hip_bfloat16* wprojT = (__hip_bfloat16*)(ws + 23068672);   // 2 MB
  __hip_bfloat16* qkvb   = (__hip_bfloat16*)(ws + 25165824);   // 50.3 MB
  __hip_bfloat16* ctx    = (__hip_bfloat16*)(ws + 75497472);   // 16 MB
  __hip_bfloat16* vt2    = (__hip_bfloat16*)(ws + 91750400);   // 16 MB

  cast_f32_bf16<<<8192, 256, 0, stream>>>(x, xb, M_ * D_);
  transpose_cast<<<dim3(N3_ / 32, D_ / 32), dim3(32, 8), 0, stream>>>(
      w_qkv, wqkvT, D_, N3_);
  transpose_cast<<<dim3(D_ / 32, D_ / 32), dim3(32, 8), 0, stream>>>(
      w_proj, wprojT, D_, D_);

  gemm_bt_bias<__hip_bfloat16, true>
      <<<dim3(N3_ / 128, M_ / 128), 256, 0, stream>>>(
          xb, wqkvT, b_qkv, qkvb, vt2, M_, N3_, D_);

  attn_causal<<<1024, 256, 0, stream>>>(qkvb, vt2, ctx);

  gemm_bt_bias<float, false><<<dim3(D_ / 128, M_ / 128), 256, 0, stream>>>(
      ctx, wprojT, b_proj, out, (__hip_bfloat16*)nullptr, M_, D_, D_);
}